// Round 1
// baseline (166.050 us; speedup 1.0000x reference)
//
#include <hip/hip_runtime.h>
#include <hip/hip_cooperative_groups.h>

namespace cg = cooperative_groups;

// HebbianNet: 3x (GEMV-ish layer + linearized hebbian shift). ALL FP32.
// conv1(1x1,3->MH) -> conv2(1x1,MH->1) with no nonlinearity is a single
// affine map of (vi, w, vj):
//   shift = r*(a0*vi + a1*W + a2*vj + cc),  a_c = sum_h cw2[h]*cw1[h][c],
//   cc = sum_h cw2[h]*cb1[h] + cb2,         r = RATE/batch_num
// => out[b,o] = vj + r*(a0*Sum_i v^2 + a1*dot[b,o] + (a2*vj + cc)*Sum_i v)
// with dot = v@W^T (pre-bias), vj = relu(dot + bias).
//
// FUSED version: one cooperative kernel, 256 blocks x 256 threads (1 block/CU).
// All three layers' weight rows are prefetched into VGPRs at t=0 (48 VGPRs of
// weights per wave) so the full ~10 MB of HBM weight traffic is in flight
// concurrently (BW-bound, ~2 us) instead of three serialized latency-bound
// phases. grid.sync() between layers replaces 2 kernel launches.

#define RATE_F 0.001f

__device__ __forceinline__ void stage_v(const float* __restrict__ vin,
                                        float* __restrict__ vsh, int tid)
{
    const float4* p = (const float4*)vin;       // 8192 f32 = 2048 float4
    float4* q = (float4*)vsh;
    #pragma unroll
    for (int k = 0; k < 8; k++) q[tid + k * 256] = p[tid + k * 256];
}

__device__ __forceinline__ void batch_sums(const float* __restrict__ vsh,
                                           float* __restrict__ svs,
                                           float* __restrict__ s2s, int tid)
{
    const int b = tid >> 5, j = tid & 31;       // 32 threads per batch row
    float sv = 0.f, s2 = 0.f;
    #pragma unroll
    for (int k = 0; k < 8; k++) {
        const float4 v = *(const float4*)&vsh[b * 1024 + (j + k * 32) * 4];
        sv += v.x + v.y + v.z + v.w;
        s2 += v.x * v.x + v.y * v.y + v.z * v.z + v.w * v.w;
    }
    #pragma unroll
    for (int m = 16; m >= 1; m >>= 1) {         // stays within 32-lane halves
        sv += __shfl_xor(sv, m, 64);
        s2 += __shfl_xor(s2, m, 64);
    }
    if (j == 0) { svs[b] = sv; s2s[b] = s2; }
}

__device__ __forceinline__ void layer_compute(
    const float4 wr[4], float bias_o, bool active,
    const float* __restrict__ vsh,
    const float* __restrict__ svs, const float* __restrict__ s2s,
    const float* __restrict__ coeff,
    float* __restrict__ vout, int o, int n_out, int lane)
{
    if (!active) return;
    float acc[8] = {0.f, 0.f, 0.f, 0.f, 0.f, 0.f, 0.f, 0.f};
    // lane-contiguous float4 reads: lane l reads 16B at byte l*16 -> banks
    // fully balanced (8 dwords/bank = data-volume minimum), vs the old
    // lane*8-float layout which aliased lanes mod 4 (2x LDS serialization).
    #pragma unroll
    for (int u = 0; u < 4; u++) {
        const float4 wv = wr[u];
        #pragma unroll
        for (int b = 0; b < 8; b++) {
            const float4 v = *(const float4*)&vsh[b * 1024 + (u * 64 + lane) * 4];
            acc[b] += wv.x * v.x + wv.y * v.y + wv.z * v.z + wv.w * v.w;
        }
    }
    #pragma unroll
    for (int b = 0; b < 8; b++) {
        #pragma unroll
        for (int m = 32; m >= 1; m >>= 1)
            acc[b] += __shfl_xor(acc[b], m, 64);
    }
    if (lane < 8) {
        const int b = lane;
        const float dot = acc[b];
        float vj = dot + bias_o;
        vj = vj > 0.f ? vj : 0.f;
        const float r = coeff[4];
        const float outv = vj + r * (coeff[0] * s2s[b] + coeff[1] * dot
                                     + (coeff[2] * vj + coeff[3]) * svs[b]);
        vout[(size_t)b * n_out + o] = outv;
    }
}

__global__ __launch_bounds__(256) void hebb_fused(
    const float* __restrict__ x,
    const float* __restrict__ W1, const float* __restrict__ b1,
    const float* __restrict__ W2, const float* __restrict__ b2,
    const float* __restrict__ W3, const float* __restrict__ b3,
    const float* __restrict__ cw1, const float* __restrict__ cb1,
    const float* __restrict__ cw2, const float* __restrict__ cb2,
    const int* __restrict__ batch_num,
    float* __restrict__ v1, float* __restrict__ v2, float* __restrict__ out)
{
    __shared__ __align__(16) float vsh[8 * 1024];   // 32 KB staged activations
    __shared__ float coeff[8];
    __shared__ float svs[8], s2s[8];

    const int tid  = threadIdx.x;
    const int w    = tid >> 6, lane = tid & 63;
    const int blk  = blockIdx.x;
    const int o12  = blk * 4 + w;            // layer 1/2 row (0..1023)
    const int o3   = blk * 2 + w;            // layer 3 row (waves 0,1 only)
    const bool act3 = (w < 2);

    // ---- prefetch ALL three layers' weight rows into registers, issued now.
    // All ~10 MB of weight traffic is in flight concurrently; layers 2/3
    // consume them from VGPRs with zero HBM latency on the critical path.
    float4 w1r[4], w2r[4], w3r[4];
    {
        const float4* r1 = (const float4*)(W1 + (size_t)o12 * 1024);
        const float4* r2 = (const float4*)(W2 + (size_t)o12 * 1024);
        const float4* r3 = (const float4*)(W3 + (size_t)(act3 ? o3 : 0) * 1024);
        #pragma unroll
        for (int u = 0; u < 4; u++) {
            w1r[u] = r1[u * 64 + lane];
            w2r[u] = r2[u * 64 + lane];
            w3r[u] = r3[u * 64 + lane];
        }
    }
    const float bias1 = b1[o12];
    const float bias2 = b2[o12];
    const float bias3 = b3[act3 ? o3 : 0];

    stage_v(x, vsh, tid);

    if (tid == 0) {
        float a0 = 0.f, a1 = 0.f, a2 = 0.f, cc = 0.f;
        #pragma unroll
        for (int h = 0; h < 8; h++) {
            const float w2c = cw2[h];
            a0 += w2c * cw1[h * 3 + 0];
            a1 += w2c * cw1[h * 3 + 1];
            a2 += w2c * cw1[h * 3 + 2];
            cc += w2c * cb1[h];
        }
        cc += cb2[0];
        coeff[0] = a0; coeff[1] = a1; coeff[2] = a2; coeff[3] = cc;
        coeff[4] = RATE_F / (float)batch_num[0];
    }
    __syncthreads();
    batch_sums(vsh, svs, s2s, tid);
    __syncthreads();
    layer_compute(w1r, bias1, true, vsh, svs, s2s, coeff, v1, o12, 1024, lane);

    cg::this_grid().sync();

    stage_v(v1, vsh, tid);
    __syncthreads();
    batch_sums(vsh, svs, s2s, tid);
    __syncthreads();
    layer_compute(w2r, bias2, true, vsh, svs, s2s, coeff, v2, o12, 1024, lane);

    cg::this_grid().sync();

    stage_v(v2, vsh, tid);
    __syncthreads();
    batch_sums(vsh, svs, s2s, tid);
    __syncthreads();
    layer_compute(w3r, bias3, act3, vsh, svs, s2s, coeff, out, o3, 512, lane);
}

// ---------------- fallback: proven 3-kernel path (99.6 us) ----------------
__global__ __launch_bounds__(256) void hebb_layer(
    const float* __restrict__ vin, const float* __restrict__ W,
    const float* __restrict__ bias,
    const float* __restrict__ cw1, const float* __restrict__ cb1,
    const float* __restrict__ cw2, const float* __restrict__ cb2,
    const int* __restrict__ batch_num,
    float* __restrict__ vout, int n_out)
{
    constexpr int NIN = 1024;
    __shared__ __align__(16) float vsh[8 * NIN];
    __shared__ float coeff[8];
    __shared__ float svs[8], s2s[8];

    const int tid = threadIdx.x;
    stage_v(vin, vsh, tid);
    if (tid == 0) {
        float a0 = 0.f, a1 = 0.f, a2 = 0.f, cc = 0.f;
        #pragma unroll
        for (int h = 0; h < 8; h++) {
            float w2 = cw2[h];
            a0 += w2 * cw1[h * 3 + 0];
            a1 += w2 * cw1[h * 3 + 1];
            a2 += w2 * cw1[h * 3 + 2];
            cc += w2 * cb1[h];
        }
        cc += cb2[0];
        coeff[0] = a0; coeff[1] = a1; coeff[2] = a2; coeff[3] = cc;
        coeff[4] = RATE_F / (float)batch_num[0];
    }
    __syncthreads();
    batch_sums(vsh, svs, s2s, tid);
    __syncthreads();

    const int w = tid >> 6, lane = tid & 63;
    const int o = blockIdx.x * 4 + w;
    if (o >= n_out) return;

    float4 wr[4];
    const float4* Wrow = (const float4*)(W + (size_t)o * NIN);
    #pragma unroll
    for (int u = 0; u < 4; u++) wr[u] = Wrow[u * 64 + lane];

    layer_compute(wr, bias[o], true, vsh, svs, s2s, coeff, vout, o, n_out, lane);
}

extern "C" void kernel_launch(void* const* d_in, const int* in_sizes, int n_in,
                              void* d_out, int out_size, void* d_ws, size_t ws_size,
                              hipStream_t stream) {
    const float* x   = (const float*)d_in[0];
    const float* W1  = (const float*)d_in[1];
    const float* b1  = (const float*)d_in[2];
    const float* W2  = (const float*)d_in[3];
    const float* b2  = (const float*)d_in[4];
    const float* W3  = (const float*)d_in[5];
    const float* b3  = (const float*)d_in[6];
    const float* cw1 = (const float*)d_in[7];
    const float* cb1 = (const float*)d_in[8];
    const float* cw2 = (const float*)d_in[9];
    const float* cb2 = (const float*)d_in[10];
    const int*   bn  = (const int*)d_in[11];

    float* v1  = (float*)d_ws;        // 8x1024 fp32 intermediate
    float* v2  = v1 + 8 * 1024;       // 8x1024 fp32 intermediate
    float* out = (float*)d_out;

    void* args[] = { (void*)&x,  (void*)&W1, (void*)&b1, (void*)&W2, (void*)&b2,
                     (void*)&W3, (void*)&b3, (void*)&cw1, (void*)&cb1,
                     (void*)&cw2, (void*)&cb2, (void*)&bn,
                     (void*)&v1, (void*)&v2, (void*)&out };
    hipError_t err = hipLaunchCooperativeKernel((const void*)hebb_fused,
                                                dim3(256), dim3(256),
                                                args, 0u, stream);
    if (err != hipSuccess) {
        // graph-capture or co-residency rejection: proven 3-kernel fallback
        hebb_layer<<<256, 256, 0, stream>>>(x,  W1, b1, cw1, cb1, cw2, cb2, bn, v1, 1024);
        hebb_layer<<<256, 256, 0, stream>>>(v1, W2, b2, cw1, cb1, cw2, cb2, bn, v2, 1024);
        hebb_layer<<<128, 256, 0, stream>>>(v2, W3, b3, cw1, cb1, cw2, cb2, bn, out, 512);
    }
}

// Round 2
// 149.512 us; speedup vs baseline: 1.1106x; 1.1106x over previous
//
#include <hip/hip_runtime.h>

// HebbianNet: 3x (GEMV-ish layer + linearized hebbian shift). ALL FP32.
// conv1(1x1,3->MH) -> conv2(1x1,MH->1) with no nonlinearity is a single
// affine map of (vi, w, vj):
//   shift = r*(a0*vi + a1*W + a2*vj + cc),  a_c = sum_h cw2[h]*cw1[h][c],
//   cc = sum_h cw2[h]*cb1[h] + cb2,         r = RATE/batch_num
// => out[b,o] = vj + r*(a0*Sum_i v^2 + a1*dot[b,o] + (a2*vj + cc)*Sum_i v)
// with dot = v@W^T (pre-bias), vj = relu(dot + bias).
//
// Round-2 structure: ONE plain (graph-capturable) kernel launch, 256 blocks
// (= CU count, 1 block/CU -> all co-resident by construction), hand-rolled
// lightweight global barrier instead of cg::grid().sync() (which measured
// ~25 us/sync via its L2 wb/inv fences + heavyweight atomic protocol), and
// no hipLaunchCooperativeKernel (which added ~110 us/iter launch overhead).
// All three layers' weight rows prefetched into VGPRs at t=0 so the whole
// ~10 MB weight stream is one overlapped BW burst and the post-barrier L2
// invalidate costs nothing (layers 2/3 never touch weights in memory again).

#define RATE_F 0.001f

__device__ __forceinline__ void stage_v(const float* __restrict__ vin,
                                        float* __restrict__ vsh, int tid)
{
    const float4* p = (const float4*)vin;       // 8192 f32 = 2048 float4
    float4* q = (float4*)vsh;
    #pragma unroll
    for (int k = 0; k < 8; k++) q[tid + k * 256] = p[tid + k * 256];
}

__device__ __forceinline__ void batch_sums(const float* __restrict__ vsh,
                                           float* __restrict__ svs,
                                           float* __restrict__ s2s, int tid)
{
    const int b = tid >> 5, j = tid & 31;       // 32 threads per batch row
    float sv = 0.f, s2 = 0.f;
    #pragma unroll
    for (int k = 0; k < 8; k++) {
        const float4 v = *(const float4*)&vsh[b * 1024 + (j + k * 32) * 4];
        sv += v.x + v.y + v.z + v.w;
        s2 += v.x * v.x + v.y * v.y + v.z * v.z + v.w * v.w;
    }
    #pragma unroll
    for (int m = 16; m >= 1; m >>= 1) {         // stays within 32-lane halves
        sv += __shfl_xor(sv, m, 64);
        s2 += __shfl_xor(s2, m, 64);
    }
    if (j == 0) { svs[b] = sv; s2s[b] = s2; }
}

__device__ __forceinline__ void layer_compute(
    const float4 wr[4], float bias_o, bool active,
    const float* __restrict__ vsh,
    const float* __restrict__ svs, const float* __restrict__ s2s,
    const float* __restrict__ coeff,
    float* __restrict__ vout, int o, int n_out, int lane)
{
    if (!active) return;
    float acc[8] = {0.f, 0.f, 0.f, 0.f, 0.f, 0.f, 0.f, 0.f};
    // lane-contiguous float4 reads: lane l reads 16B at byte l*16 -> banks
    // fully balanced (8 dwords/bank = data-volume minimum).
    #pragma unroll
    for (int u = 0; u < 4; u++) {
        const float4 wv = wr[u];
        #pragma unroll
        for (int b = 0; b < 8; b++) {
            const float4 v = *(const float4*)&vsh[b * 1024 + (u * 64 + lane) * 4];
            acc[b] += wv.x * v.x + wv.y * v.y + wv.z * v.z + wv.w * v.w;
        }
    }
    #pragma unroll
    for (int b = 0; b < 8; b++) {
        #pragma unroll
        for (int m = 32; m >= 1; m >>= 1)
            acc[b] += __shfl_xor(acc[b], m, 64);
    }
    if (lane < 8) {
        const int b = lane;
        const float dot = acc[b];
        float vj = dot + bias_o;
        vj = vj > 0.f ? vj : 0.f;
        const float r = coeff[4];
        const float outv = vj + r * (coeff[0] * s2s[b] + coeff[1] * dot
                                     + (coeff[2] * vj + coeff[3]) * svs[b]);
        vout[(size_t)b * n_out + o] = outv;
    }
}

// Lightweight grid barrier. Safe because grid == 256 == #CUs with 1 block/CU
// (92 VGPR, 33 KB LDS, 4 waves) -> all workgroups co-resident by capacity.
// Counter is zeroed by hipMemsetAsync before each launch (graph-capturable,
// re-poison-safe). Relaxed agent-scope polling loads bypass L2 (no per-poll
// invalidate); one full fence on each side gives release/acquire.
__device__ __forceinline__ void grid_bar(unsigned* cnt, unsigned nblocks)
{
    __syncthreads();
    if (threadIdx.x == 0) {
        __threadfence();  // release: drain + make this block's stores agent-visible
        __hip_atomic_fetch_add(cnt, 1u, __ATOMIC_RELAXED,
                               __HIP_MEMORY_SCOPE_AGENT);
        while (__hip_atomic_load(cnt, __ATOMIC_RELAXED,
                                 __HIP_MEMORY_SCOPE_AGENT) < nblocks)
            __builtin_amdgcn_s_sleep(2);
    }
    __syncthreads();
    __threadfence();      // acquire: invalidate L1/L2 so v-reads are fresh
}

__global__ __launch_bounds__(256) void hebb_fused(
    const float* __restrict__ x,
    const float* __restrict__ W1, const float* __restrict__ b1,
    const float* __restrict__ W2, const float* __restrict__ b2,
    const float* __restrict__ W3, const float* __restrict__ b3,
    const float* __restrict__ cw1, const float* __restrict__ cb1,
    const float* __restrict__ cw2, const float* __restrict__ cb2,
    const int* __restrict__ batch_num,
    float* __restrict__ v1, float* __restrict__ v2, float* __restrict__ out,
    unsigned* __restrict__ bar)
{
    __shared__ __align__(16) float vsh[8 * 1024];   // 32 KB staged activations
    __shared__ float coeff[8];
    __shared__ float svs[8], s2s[8];

    const int tid  = threadIdx.x;
    const int w    = tid >> 6, lane = tid & 63;
    const int blk  = blockIdx.x;
    const int o12  = blk * 4 + w;            // layer 1/2 row (0..1023)
    const int o3   = blk * 2 + w;            // layer 3 row (waves 0,1 only)
    const bool act3 = (w < 2);
    const unsigned NB = gridDim.x;

    // ---- prefetch ALL three layers' weight rows into registers, issued now.
    // Whole ~10 MB weight stream in flight as one BW burst; layers 2/3 then
    // consume weights from VGPRs (immune to the barrier's L2 invalidate).
    float4 w1r[4], w2r[4], w3r[4];
    {
        const float4* r1 = (const float4*)(W1 + (size_t)o12 * 1024);
        const float4* r2 = (const float4*)(W2 + (size_t)o12 * 1024);
        const float4* r3 = (const float4*)(W3 + (size_t)(act3 ? o3 : 0) * 1024);
        #pragma unroll
        for (int u = 0; u < 4; u++) w1r[u] = r1[u * 64 + lane];
        #pragma unroll
        for (int u = 0; u < 4; u++) w2r[u] = r2[u * 64 + lane];
        #pragma unroll
        for (int u = 0; u < 4; u++) w3r[u] = r3[u * 64 + lane];
    }
    const float bias1 = b1[o12];
    const float bias2 = b2[o12];
    const float bias3 = b3[act3 ? o3 : 0];

    stage_v(x, vsh, tid);

    if (tid == 0) {
        float a0 = 0.f, a1 = 0.f, a2 = 0.f, cc = 0.f;
        #pragma unroll
        for (int h = 0; h < 8; h++) {
            const float w2c = cw2[h];
            a0 += w2c * cw1[h * 3 + 0];
            a1 += w2c * cw1[h * 3 + 1];
            a2 += w2c * cw1[h * 3 + 2];
            cc += w2c * cb1[h];
        }
        cc += cb2[0];
        coeff[0] = a0; coeff[1] = a1; coeff[2] = a2; coeff[3] = cc;
        coeff[4] = RATE_F / (float)batch_num[0];
    }
    __syncthreads();
    batch_sums(vsh, svs, s2s, tid);
    __syncthreads();
    layer_compute(w1r, bias1, true, vsh, svs, s2s, coeff, v1, o12, 1024, lane);

    grid_bar(&bar[0], NB);

    stage_v(v1, vsh, tid);
    __syncthreads();
    batch_sums(vsh, svs, s2s, tid);
    __syncthreads();
    layer_compute(w2r, bias2, true, vsh, svs, s2s, coeff, v2, o12, 1024, lane);

    grid_bar(&bar[1], NB);

    stage_v(v2, vsh, tid);
    __syncthreads();
    batch_sums(vsh, svs, s2s, tid);
    __syncthreads();
    layer_compute(w3r, bias3, act3, vsh, svs, s2s, coeff, out, o3, 512, lane);
}

extern "C" void kernel_launch(void* const* d_in, const int* in_sizes, int n_in,
                              void* d_out, int out_size, void* d_ws, size_t ws_size,
                              hipStream_t stream) {
    const float* x   = (const float*)d_in[0];
    const float* W1  = (const float*)d_in[1];
    const float* b1  = (const float*)d_in[2];
    const float* W2  = (const float*)d_in[3];
    const float* b2  = (const float*)d_in[4];
    const float* W3  = (const float*)d_in[5];
    const float* b3  = (const float*)d_in[6];
    const float* cw1 = (const float*)d_in[7];
    const float* cb1 = (const float*)d_in[8];
    const float* cw2 = (const float*)d_in[9];
    const float* cb2 = (const float*)d_in[10];
    const int*   bn  = (const int*)d_in[11];

    float*    v1  = (float*)d_ws;            // 8x1024 fp32 intermediate
    float*    v2  = v1 + 8 * 1024;           // 8x1024 fp32 intermediate
    unsigned* bar = (unsigned*)(v2 + 8 * 1024);  // 2 barrier counters
    float*    out = (float*)d_out;

    hipMemsetAsync(bar, 0, 2 * sizeof(unsigned), stream);
    hebb_fused<<<256, 256, 0, stream>>>(x, W1, b1, W2, b2, W3, b3,
                                        cw1, cb1, cw2, cb2, bn,
                                        v1, v2, out, bar);
}

// Round 3
// 119.615 us; speedup vs baseline: 1.3882x; 1.2499x over previous
//
#include <hip/hip_runtime.h>

// HebbianNet: 3x (GEMV-ish layer + linearized hebbian shift). ALL FP32.
// conv1(1x1,3->MH) -> conv2(1x1,MH->1) with no nonlinearity is a single
// affine map of (vi, w, vj):
//   shift = r*(a0*vi + a1*W + a2*vj + cc),  a_c = sum_h cw2[h]*cw1[h][c],
//   cc = sum_h cw2[h]*cb1[h] + cb2,         r = RATE/batch_num
// => out[b,o] = vj + r*(a0*Sum_i v^2 + a1*dot[b,o] + (a2*vj + cc)*Sum_i v)
// with dot = v@W^T (pre-bias), vj = relu(dot + bias).
//
// Round-3 structure (fixing round-2's two measured pathologies):
//  * W2/W3 rows staged into LDS via global_load_lds DMA issued at t=0 —
//    LDS writes are side effects, the compiler CANNOT sink them past the
//    barriers (round-2's register "prefetch" was silently sunk: VGPR=88 < the
//    192 needed, so layers 2/3 ran latency-exposed cold weight fetches).
//  * No __threadfence() (= buffer_wbl2 + buffer_inv per block per barrier).
//    Cross-phase activations use agent-scope (sc0 sc1) stores/loads that
//    bypass the non-coherent per-XCD L2s; barrier = release-add + relaxed
//    spin + one acquire load. Dirty-L2 set at the release is ~empty.
// One plain graph-capturable launch; 256 blocks = 1 block/CU (co-resident by
// capacity: 56KB LDS, ~80 VGPR, 4 waves).

#define RATE_F 0.001f
#define AS1 __attribute__((address_space(1)))
#define AS3 __attribute__((address_space(3)))

__device__ __forceinline__ void gl_lds16(const float* g, float* l)
{
    // one instruction: 64 lanes x 16B -> LDS[l .. l+1024), l wave-uniform
    __builtin_amdgcn_global_load_lds((const AS1 void*)g, (AS3 void*)l, 16, 0, 0);
}

// cached staging (phase 1 input x only — stable across the kernel)
__device__ __forceinline__ void stage_v(const float* __restrict__ vin,
                                        float* __restrict__ vsh, int tid)
{
    const float4* p = (const float4*)vin;       // 8192 f32 = 2048 float4
    float4* q = (float4*)vsh;
    #pragma unroll
    for (int k = 0; k < 8; k++) q[tid + k * 256] = p[tid + k * 256];
}

// coherent staging (phases 2/3): agent-scope loads bypass stale L1/L2.
__device__ __forceinline__ void stage_v_coh(const float* __restrict__ vin,
                                            float* __restrict__ vsh, int tid)
{
    #pragma unroll
    for (int k = 0; k < 32; k++) {
        const int i = tid + k * 256;            // wave-coalesced dwords
        vsh[i] = __hip_atomic_load(vin + i, __ATOMIC_RELAXED,
                                   __HIP_MEMORY_SCOPE_AGENT);
    }
}

__device__ __forceinline__ void batch_sums(const float* __restrict__ vsh,
                                           float* __restrict__ svs,
                                           float* __restrict__ s2s, int tid)
{
    const int b = tid >> 5, j = tid & 31;       // 32 threads per batch row
    float sv = 0.f, s2 = 0.f;
    #pragma unroll
    for (int k = 0; k < 8; k++) {
        const float4 v = *(const float4*)&vsh[b * 1024 + (j + k * 32) * 4];
        sv += v.x + v.y + v.z + v.w;
        s2 += v.x * v.x + v.y * v.y + v.z * v.z + v.w * v.w;
    }
    #pragma unroll
    for (int m = 16; m >= 1; m >>= 1) {         // stays within 32-lane halves
        sv += __shfl_xor(sv, m, 64);
        s2 += __shfl_xor(s2, m, 64);
    }
    if (j == 0) { svs[b] = sv; s2s[b] = s2; }
}

// dot + hebbian epilogue; weights come from an LDS row (or caller's regs via
// the reg variant below). coh_store: agent-scope store (cross-phase data).
__device__ __forceinline__ void epilogue(
    float acc[8], float bias_o, const float* __restrict__ svs,
    const float* __restrict__ s2s, const float* __restrict__ coeff,
    float* __restrict__ vout, int o, int n_out, int lane, bool coh_store)
{
    #pragma unroll
    for (int b = 0; b < 8; b++) {
        #pragma unroll
        for (int m = 32; m >= 1; m >>= 1)
            acc[b] += __shfl_xor(acc[b], m, 64);
    }
    if (lane < 8) {
        const int b = lane;
        const float dot = acc[b];
        float vj = dot + bias_o;
        vj = vj > 0.f ? vj : 0.f;
        const float r = coeff[4];
        const float outv = vj + r * (coeff[0] * s2s[b] + coeff[1] * dot
                                     + (coeff[2] * vj + coeff[3]) * svs[b]);
        float* dst = vout + (size_t)b * n_out + o;
        if (coh_store)
            __hip_atomic_store(dst, outv, __ATOMIC_RELAXED,
                               __HIP_MEMORY_SCOPE_AGENT);
        else
            *dst = outv;
    }
}

__device__ __forceinline__ void layer_reg(
    const float4 wr[4], float bias_o, const float* __restrict__ vsh,
    const float* __restrict__ svs, const float* __restrict__ s2s,
    const float* __restrict__ coeff,
    float* __restrict__ vout, int o, int n_out, int lane, bool coh_store)
{
    float acc[8] = {0.f, 0.f, 0.f, 0.f, 0.f, 0.f, 0.f, 0.f};
    #pragma unroll
    for (int u = 0; u < 4; u++) {
        const float4 wv = wr[u];
        #pragma unroll
        for (int b = 0; b < 8; b++) {
            const float4 v = *(const float4*)&vsh[b * 1024 + (u * 64 + lane) * 4];
            acc[b] += wv.x * v.x + wv.y * v.y + wv.z * v.z + wv.w * v.w;
        }
    }
    epilogue(acc, bias_o, svs, s2s, coeff, vout, o, n_out, lane, coh_store);
}

__device__ __forceinline__ void layer_lds(
    const float* __restrict__ wlds, float bias_o, const float* __restrict__ vsh,
    const float* __restrict__ svs, const float* __restrict__ s2s,
    const float* __restrict__ coeff,
    float* __restrict__ vout, int o, int n_out, int lane, bool coh_store)
{
    float acc[8] = {0.f, 0.f, 0.f, 0.f, 0.f, 0.f, 0.f, 0.f};
    #pragma unroll
    for (int u = 0; u < 4; u++) {
        const float4 wv = *(const float4*)&wlds[(u * 64 + lane) * 4];
        #pragma unroll
        for (int b = 0; b < 8; b++) {
            const float4 v = *(const float4*)&vsh[b * 1024 + (u * 64 + lane) * 4];
            acc[b] += wv.x * v.x + wv.y * v.y + wv.z * v.z + wv.w * v.w;
        }
    }
    epilogue(acc, bias_o, svs, s2s, coeff, vout, o, n_out, lane, coh_store);
}

// Lightweight grid barrier — no cache-wide fences. Safe: 256 blocks on 256
// CUs (1 block/CU, co-resident by capacity); counters zeroed by the memset
// dispatch each launch. The release-add drains vmcnt and writes back the
// (empty) dirty L2 set; cross-phase data never lives in L2 (sc0 sc1).
__device__ __forceinline__ void grid_bar(unsigned* cnt, unsigned nblocks)
{
    __syncthreads();   // also drains every wave's outstanding vmem (incl. DMA)
    if (threadIdx.x == 0) {
        __hip_atomic_fetch_add(cnt, 1u, __ATOMIC_RELEASE,
                               __HIP_MEMORY_SCOPE_AGENT);
        while (__hip_atomic_load(cnt, __ATOMIC_RELAXED,
                                 __HIP_MEMORY_SCOPE_AGENT) < nblocks)
            __builtin_amdgcn_s_sleep(8);
        (void)__hip_atomic_load(cnt, __ATOMIC_ACQUIRE,
                                __HIP_MEMORY_SCOPE_AGENT);
    }
    __syncthreads();
}

__global__ __launch_bounds__(256) void hebb_fused(
    const float* __restrict__ x,
    const float* __restrict__ W1, const float* __restrict__ b1,
    const float* __restrict__ W2, const float* __restrict__ b2,
    const float* __restrict__ W3, const float* __restrict__ b3,
    const float* __restrict__ cw1, const float* __restrict__ cb1,
    const float* __restrict__ cw2, const float* __restrict__ cb2,
    const int* __restrict__ batch_num,
    float* __restrict__ v1, float* __restrict__ v2, float* __restrict__ out,
    unsigned* __restrict__ bar)
{
    __shared__ __align__(16) float vsh[8 * 1024];   // 32 KB activations
    __shared__ __align__(16) float w2sh[4 * 1024];  // 16 KB: W2 rows, 1/wave
    __shared__ __align__(16) float w3sh[2 * 1024];  // 8 KB: W3 rows (waves 0,1)
    __shared__ float coeff[8];
    __shared__ float svs[8], s2s[8];

    const int tid  = threadIdx.x;
    const int w    = tid >> 6, lane = tid & 63;
    const int blk  = blockIdx.x;
    const int o12  = blk * 4 + w;            // layer 1/2 row (0..1023)
    const int o3   = blk * 2 + w;            // layer 3 row (waves 0,1)
    const bool act3 = (w < 2);
    const unsigned NB = gridDim.x;

    // ---- t=0: DMA-stage W2/W3 rows into LDS. These are memory side effects,
    // so unlike round-2's register prefetch the compiler cannot sink them
    // past the barriers — the whole weight stream is genuinely in flight now.
    {
        const float* g2 = W2 + (size_t)o12 * 1024 + lane * 4;
        float* l2 = w2sh + w * 1024;                 // wave-uniform dest
        #pragma unroll
        for (int c = 0; c < 4; c++) gl_lds16(g2 + c * 256, l2 + c * 256);
        if (w >= 2) {                                // waves 2,3 stage W3 rows
            const int r = w - 2;
            const float* g3 = W3 + (size_t)(blk * 2 + r) * 1024 + lane * 4;
            float* l3 = w3sh + r * 1024;
            #pragma unroll
            for (int c = 0; c < 4; c++) gl_lds16(g3 + c * 256, l3 + c * 256);
        }
    }

    // ---- layer-1 weight row into registers (16 VGPRs; fits, stays) ----
    float4 w1r[4];
    {
        const float4* r1 = (const float4*)(W1 + (size_t)o12 * 1024);
        #pragma unroll
        for (int u = 0; u < 4; u++) w1r[u] = r1[u * 64 + lane];
    }
    const float bias1 = b1[o12];
    const float bias2 = b2[o12];
    const float bias3 = act3 ? b3[o3] : 0.f;

    stage_v(x, vsh, tid);

    if (tid == 0) {
        float a0 = 0.f, a1 = 0.f, a2 = 0.f, cc = 0.f;
        #pragma unroll
        for (int h = 0; h < 8; h++) {
            const float w2c = cw2[h];
            a0 += w2c * cw1[h * 3 + 0];
            a1 += w2c * cw1[h * 3 + 1];
            a2 += w2c * cw1[h * 3 + 2];
            cc += w2c * cb1[h];
        }
        cc += cb2[0];
        coeff[0] = a0; coeff[1] = a1; coeff[2] = a2; coeff[3] = cc;
        coeff[4] = RATE_F / (float)batch_num[0];
    }
    __syncthreads();
    batch_sums(vsh, svs, s2s, tid);
    __syncthreads();
    layer_reg(w1r, bias1, vsh, svs, s2s, coeff, v1, o12, 1024, lane, true);

    grid_bar(&bar[0], NB);

    stage_v_coh(v1, vsh, tid);
    __syncthreads();
    batch_sums(vsh, svs, s2s, tid);
    __syncthreads();
    layer_lds(w2sh + w * 1024, bias2, vsh, svs, s2s, coeff, v2, o12, 1024,
              lane, true);

    grid_bar(&bar[1], NB);

    stage_v_coh(v2, vsh, tid);
    __syncthreads();
    batch_sums(vsh, svs, s2s, tid);
    __syncthreads();
    if (act3)
        layer_lds(w3sh + w * 1024, bias3, vsh, svs, s2s, coeff, out, o3, 512,
                  lane, false);
}

extern "C" void kernel_launch(void* const* d_in, const int* in_sizes, int n_in,
                              void* d_out, int out_size, void* d_ws, size_t ws_size,
                              hipStream_t stream) {
    const float* x   = (const float*)d_in[0];
    const float* W1  = (const float*)d_in[1];
    const float* b1  = (const float*)d_in[2];
    const float* W2  = (const float*)d_in[3];
    const float* b2  = (const float*)d_in[4];
    const float* W3  = (const float*)d_in[5];
    const float* b3  = (const float*)d_in[6];
    const float* cw1 = (const float*)d_in[7];
    const float* cb1 = (const float*)d_in[8];
    const float* cw2 = (const float*)d_in[9];
    const float* cb2 = (const float*)d_in[10];
    const int*   bn  = (const int*)d_in[11];

    float*    v1  = (float*)d_ws;            // 8x1024 fp32 intermediate
    float*    v2  = v1 + 8 * 1024;           // 8x1024 fp32 intermediate
    unsigned* bar = (unsigned*)(v2 + 8 * 1024);  // 2 barrier counters
    float*    out = (float*)d_out;

    hipMemsetAsync(bar, 0, 2 * sizeof(unsigned), stream);
    hebb_fused<<<256, 256, 0, stream>>>(x, W1, b1, W2, b2, W3, b3,
                                        cw1, cb1, cw2, cb2, bn,
                                        v1, v2, out, bar);
}

// Round 5
// 103.577 us; speedup vs baseline: 1.6032x; 1.1548x over previous
//
#include <hip/hip_runtime.h>

// HebbianNet: 3x (GEMV-ish layer + linearized hebbian shift). ALL FP32.
// conv1(1x1,3->MH) -> conv2(1x1,MH->1) with no nonlinearity is a single
// affine map of (vi, w, vj):
//   shift = r*(a0*vi + a1*W + a2*vj + cc),  a_c = sum_h cw2[h]*cw1[h][c],
//   cc = sum_h cw2[h]*cb1[h] + cb2,         r = RATE/batch_num
// => out[b,o] = vj + r*(a0*Sum_i v^2 + a1*dot[b,o] + (a2*vj + cc)*Sum_i v)
// with dot = v@W^T (pre-bias), vj = relu(dot + bias).
//
// Round-5 = round-4 resubmitted (round-4 bench was an infra failure, no
// counters). Measured ladder: 73us (2 full fences/block/barrier) -> 41.5us
// (1 split fence/block/barrier) -- time scales with the count of
// buffer_wbl2/buffer_inv cache-maintenance ops, not with work. This version
// removes ALL release/acquire semantics: the barrier is pure-relaxed.
// Correct because every cross-phase byte (v1/v2) moves via agent-scope
// sc0|sc1 stores/loads that bypass the non-coherent per-XCD L2s (IF is the
// coherence point), and ordering is structural: __syncthreads() compiles to
// s_waitcnt vmcnt(0) before s_barrier, so each block's v-stores have
// COMPLETED at IF before its relaxed atomicAdd; a spinner seeing cnt==NB
// therefore sees completed stores, and its sc0|sc1 reads fetch from IF.
// Zero wbl2/inv instructions anywhere in the kernel.
//
// Weights: W2/W3 rows staged to LDS via global_load_lds DMA issued at t=0
// (side effects -- cannot be sunk past barriers, unlike round-2's register
// prefetch which the compiler silently sank). W1 row in 16 VGPRs.
// One plain graph-capturable launch; 256 blocks = 1 block/CU.

#define RATE_F 0.001f
#define AS1 __attribute__((address_space(1)))
#define AS3 __attribute__((address_space(3)))

__device__ __forceinline__ void gl_lds16(const float* g, float* l)
{
    // one instruction: 64 lanes x 16B -> LDS[l .. l+1024), l wave-uniform
    __builtin_amdgcn_global_load_lds((const AS1 void*)g, (AS3 void*)l, 16, 0, 0);
}

// cached staging (phase 1 input x only — stable across the kernel)
__device__ __forceinline__ void stage_v(const float* __restrict__ vin,
                                        float* __restrict__ vsh, int tid)
{
    const float4* p = (const float4*)vin;       // 8192 f32 = 2048 float4
    float4* q = (float4*)vsh;
    #pragma unroll
    for (int k = 0; k < 8; k++) q[tid + k * 256] = p[tid + k * 256];
}

// coherent staging (phases 2/3): agent-scope loads bypass stale L1/L2,
// fetch from IF (the coherence point). 8B granules: 16 issues/thread.
__device__ __forceinline__ void stage_v_coh(const float* __restrict__ vin,
                                            float* __restrict__ vsh, int tid)
{
    const unsigned long long* p = (const unsigned long long*)vin; // 4096 qwords
    unsigned long long* q = (unsigned long long*)vsh;
    #pragma unroll
    for (int k = 0; k < 16; k++) {
        const int i = tid + k * 256;            // wave-coalesced qwords
        q[i] = __hip_atomic_load(p + i, __ATOMIC_RELAXED,
                                 __HIP_MEMORY_SCOPE_AGENT);
    }
}

__device__ __forceinline__ void batch_sums(const float* __restrict__ vsh,
                                           float* __restrict__ svs,
                                           float* __restrict__ s2s, int tid)
{
    const int b = tid >> 5, j = tid & 31;       // 32 threads per batch row
    float sv = 0.f, s2 = 0.f;
    #pragma unroll
    for (int k = 0; k < 8; k++) {
        const float4 v = *(const float4*)&vsh[b * 1024 + (j + k * 32) * 4];
        sv += v.x + v.y + v.z + v.w;
        s2 += v.x * v.x + v.y * v.y + v.z * v.z + v.w * v.w;
    }
    #pragma unroll
    for (int m = 16; m >= 1; m >>= 1) {         // stays within 32-lane halves
        sv += __shfl_xor(sv, m, 64);
        s2 += __shfl_xor(s2, m, 64);
    }
    if (j == 0) { svs[b] = sv; s2s[b] = s2; }
}

__device__ __forceinline__ void epilogue(
    float acc[8], float bias_o, const float* __restrict__ svs,
    const float* __restrict__ s2s, const float* __restrict__ coeff,
    float* __restrict__ vout, int o, int n_out, int lane, bool coh_store)
{
    #pragma unroll
    for (int b = 0; b < 8; b++) {
        #pragma unroll
        for (int m = 32; m >= 1; m >>= 1)
            acc[b] += __shfl_xor(acc[b], m, 64);
    }
    if (lane < 8) {
        const int b = lane;
        const float dot = acc[b];
        float vj = dot + bias_o;
        vj = vj > 0.f ? vj : 0.f;
        const float r = coeff[4];
        const float outv = vj + r * (coeff[0] * s2s[b] + coeff[1] * dot
                                     + (coeff[2] * vj + coeff[3]) * svs[b]);
        float* dst = vout + (size_t)b * n_out + o;
        if (coh_store)
            __hip_atomic_store(dst, outv, __ATOMIC_RELAXED,
                               __HIP_MEMORY_SCOPE_AGENT);
        else
            *dst = outv;
    }
}

__device__ __forceinline__ void layer_reg(
    const float4 wr[4], float bias_o, const float* __restrict__ vsh,
    const float* __restrict__ svs, const float* __restrict__ s2s,
    const float* __restrict__ coeff,
    float* __restrict__ vout, int o, int n_out, int lane, bool coh_store)
{
    float acc[8] = {0.f, 0.f, 0.f, 0.f, 0.f, 0.f, 0.f, 0.f};
    #pragma unroll
    for (int u = 0; u < 4; u++) {
        const float4 wv = wr[u];
        #pragma unroll
        for (int b = 0; b < 8; b++) {
            const float4 v = *(const float4*)&vsh[b * 1024 + (u * 64 + lane) * 4];
            acc[b] += wv.x * v.x + wv.y * v.y + wv.z * v.z + wv.w * v.w;
        }
    }
    epilogue(acc, bias_o, svs, s2s, coeff, vout, o, n_out, lane, coh_store);
}

__device__ __forceinline__ void layer_lds(
    const float* __restrict__ wlds, float bias_o, const float* __restrict__ vsh,
    const float* __restrict__ svs, const float* __restrict__ s2s,
    const float* __restrict__ coeff,
    float* __restrict__ vout, int o, int n_out, int lane, bool coh_store)
{
    float acc[8] = {0.f, 0.f, 0.f, 0.f, 0.f, 0.f, 0.f, 0.f};
    #pragma unroll
    for (int u = 0; u < 4; u++) {
        const float4 wv = *(const float4*)&wlds[(u * 64 + lane) * 4];
        #pragma unroll
        for (int b = 0; b < 8; b++) {
            const float4 v = *(const float4*)&vsh[b * 1024 + (u * 64 + lane) * 4];
            acc[b] += wv.x * v.x + wv.y * v.y + wv.z * v.z + wv.w * v.w;
        }
    }
    epilogue(acc, bias_o, svs, s2s, coeff, vout, o, n_out, lane, coh_store);
}

// Pure-relaxed grid barrier: NO buffer_wbl2 / buffer_inv anywhere.
// Safe: 256 blocks on 256 CUs (co-resident by capacity); counters zeroed by
// the memset dispatch each launch (replay without memset sees cnt>=NB and
// falls through -- no hang). Visibility argument in the header comment.
__device__ __forceinline__ void grid_bar(unsigned* cnt, unsigned nblocks)
{
    __syncthreads();   // s_waitcnt vmcnt(0): block's sc0|sc1 stores COMPLETE
    if (threadIdx.x == 0) {
        __hip_atomic_fetch_add(cnt, 1u, __ATOMIC_RELAXED,
                               __HIP_MEMORY_SCOPE_AGENT);
        while (__hip_atomic_load(cnt, __ATOMIC_RELAXED,
                                 __HIP_MEMORY_SCOPE_AGENT) < nblocks)
            __builtin_amdgcn_s_sleep(2);
    }
    __syncthreads();
}

__global__ __launch_bounds__(256) void hebb_fused(
    const float* __restrict__ x,
    const float* __restrict__ W1, const float* __restrict__ b1,
    const float* __restrict__ W2, const float* __restrict__ b2,
    const float* __restrict__ W3, const float* __restrict__ b3,
    const float* __restrict__ cw1, const float* __restrict__ cb1,
    const float* __restrict__ cw2, const float* __restrict__ cb2,
    const int* __restrict__ batch_num,
    float* __restrict__ v1, float* __restrict__ v2, float* __restrict__ out,
    unsigned* __restrict__ bar)
{
    __shared__ __align__(16) float vsh[8 * 1024];   // 32 KB activations
    __shared__ __align__(16) float w2sh[4 * 1024];  // 16 KB: W2 rows, 1/wave
    __shared__ __align__(16) float w3sh[2 * 1024];  // 8 KB: W3 rows (waves 0,1)
    __shared__ float coeff[8];
    __shared__ float svs[8], s2s[8];

    const int tid  = threadIdx.x;
    const int w    = tid >> 6, lane = tid & 63;
    const int blk  = blockIdx.x;
    const int o12  = blk * 4 + w;            // layer 1/2 row (0..1023)
    const int o3   = blk * 2 + w;            // layer 3 row (waves 0,1)
    const bool act3 = (w < 2);
    const unsigned NB = gridDim.x;

    // ---- t=0: DMA-stage W2/W3 rows into LDS (cannot be sunk past barriers).
    {
        const float* g2 = W2 + (size_t)o12 * 1024 + lane * 4;
        float* l2 = w2sh + w * 1024;                 // wave-uniform dest
        #pragma unroll
        for (int c = 0; c < 4; c++) gl_lds16(g2 + c * 256, l2 + c * 256);
        if (w >= 2) {                                // waves 2,3 stage W3 rows
            const int r = w - 2;
            const float* g3 = W3 + (size_t)(blk * 2 + r) * 1024 + lane * 4;
            float* l3 = w3sh + r * 1024;
            #pragma unroll
            for (int c = 0; c < 4; c++) gl_lds16(g3 + c * 256, l3 + c * 256);
        }
    }

    // ---- layer-1 weight row into registers (16 VGPRs; fits, stays) ----
    float4 w1r[4];
    {
        const float4* r1 = (const float4*)(W1 + (size_t)o12 * 1024);
        #pragma unroll
        for (int u = 0; u < 4; u++) w1r[u] = r1[u * 64 + lane];
    }
    const float bias1 = b1[o12];
    const float bias2 = b2[o12];
    const float bias3 = act3 ? b3[o3] : 0.f;

    stage_v(x, vsh, tid);

    if (tid == 0) {
        float a0 = 0.f, a1 = 0.f, a2 = 0.f, cc = 0.f;
        #pragma unroll
        for (int h = 0; h < 8; h++) {
            const float w2c = cw2[h];
            a0 += w2c * cw1[h * 3 + 0];
            a1 += w2c * cw1[h * 3 + 1];
            a2 += w2c * cw1[h * 3 + 2];
            cc += w2c * cb1[h];
        }
        cc += cb2[0];
        coeff[0] = a0; coeff[1] = a1; coeff[2] = a2; coeff[3] = cc;
        coeff[4] = RATE_F / (float)batch_num[0];
    }
    __syncthreads();
    batch_sums(vsh, svs, s2s, tid);
    __syncthreads();
    layer_reg(w1r, bias1, vsh, svs, s2s, coeff, v1, o12, 1024, lane, true);

    grid_bar(&bar[0], NB);

    stage_v_coh(v1, vsh, tid);
    __syncthreads();
    batch_sums(vsh, svs, s2s, tid);
    __syncthreads();
    layer_lds(w2sh + w * 1024, bias2, vsh, svs, s2s, coeff, v2, o12, 1024,
              lane, true);

    grid_bar(&bar[1], NB);

    stage_v_coh(v2, vsh, tid);
    __syncthreads();
    batch_sums(vsh, svs, s2s, tid);
    __syncthreads();
    if (act3)
        layer_lds(w3sh + w * 1024, bias3, vsh, svs, s2s, coeff, out, o3, 512,
                  lane, false);
}

extern "C" void kernel_launch(void* const* d_in, const int* in_sizes, int n_in,
                              void* d_out, int out_size, void* d_ws, size_t ws_size,
                              hipStream_t stream) {
    const float* x   = (const float*)d_in[0];
    const float* W1  = (const float*)d_in[1];
    const float* b1  = (const float*)d_in[2];
    const float* W2  = (const float*)d_in[3];
    const float* b2  = (const float*)d_in[4];
    const float* W3  = (const float*)d_in[5];
    const float* b3  = (const float*)d_in[6];
    const float* cw1 = (const float*)d_in[7];
    const float* cb1 = (const float*)d_in[8];
    const float* cw2 = (const float*)d_in[9];
    const float* cb2 = (const float*)d_in[10];
    const int*   bn  = (const int*)d_in[11];

    float*    v1  = (float*)d_ws;            // 8x1024 fp32 intermediate
    float*    v2  = v1 + 8 * 1024;           // 8x1024 fp32 intermediate
    unsigned* bar = (unsigned*)(v2 + 8 * 1024);  // 2 barrier counters
    float*    out = (float*)d_out;

    hipMemsetAsync(bar, 0, 2 * sizeof(unsigned), stream);
    hebb_fused<<<256, 256, 0, stream>>>(x, W1, b1, W2, b2, W3, b3,
                                        cw1, cb1, cw2, cb2, bn,
                                        v1, v2, out, bar);
}

// Round 6
// 99.849 us; speedup vs baseline: 1.6630x; 1.0373x over previous
//
#include <hip/hip_runtime.h>

// HebbianNet: 3x (GEMV-ish layer + linearized hebbian shift). ALL FP32.
// conv1(1x1,3->MH) -> conv2(1x1,MH->1) with no nonlinearity is a single
// affine map of (vi, w, vj):
//   shift = r*(a0*vi + a1*W + a2*vj + cc),  a_c = sum_h cw2[h]*cw1[h][c],
//   cc = sum_h cw2[h]*cb1[h] + cb2,         r = RATE/batch_num
// => out[b,o] = vj + r*(a0*Sum_i v^2 + a1*dot[b,o] + (a2*vj + cc)*Sum_i v)
// with dot = v@W^T (pre-bias), vj = relu(dot + bias).
//
// Round-6: fence ladder done (73us -> 41.5us -> ~25us as cache-maintenance
// ops per block per barrier went 2 -> 1 -> 0). Residual ~25us >> ~6us of
// work; flat-RMW arrival is only ~0.5us/barrier, so the prime suspect is
// WORKGROUP DISPATCH SKEW: no block passes barrier 1 until the LAST of the
// grid's workgroups is dispatched + through phase 1. This round halves the
// grid: 128 blocks x 512 threads (8 waves = 8 rows/block for L1/L2, 4 rows
// for L3). 82KB LDS -> hard 1 block/CU, 128 <= 256 CUs: co-resident by
// capacity. Barrier algo unchanged from round 5 (pure-relaxed, zero
// wbl2/inv; sc0|sc1 agent ops through IF for all cross-phase bytes;
// ordering structural via __syncthreads' s_waitcnt vmcnt(0)). Counters on
// separate 128B cachelines.

#define RATE_F 0.001f
#define AS1 __attribute__((address_space(1)))
#define AS3 __attribute__((address_space(3)))

#define NBLK 128
#define TPB  512

__device__ __forceinline__ void gl_lds16(const float* g, float* l)
{
    // one instruction: 64 lanes x 16B -> LDS[l .. l+1024), l wave-uniform
    __builtin_amdgcn_global_load_lds((const AS1 void*)g, (AS3 void*)l, 16, 0, 0);
}

// cached staging (phase 1 input x only — stable across the kernel)
__device__ __forceinline__ void stage_v(const float* __restrict__ vin,
                                        float* __restrict__ vsh, int tid)
{
    const float4* p = (const float4*)vin;       // 8192 f32 = 2048 float4
    float4* q = (float4*)vsh;
    #pragma unroll
    for (int k = 0; k < 4; k++) q[tid + k * TPB] = p[tid + k * TPB];
}

// coherent staging (phases 2/3): agent-scope loads bypass stale L1/L2,
// fetch from IF (the coherence point). 8B granules: 8 issues/thread.
__device__ __forceinline__ void stage_v_coh(const float* __restrict__ vin,
                                            float* __restrict__ vsh, int tid)
{
    const unsigned long long* p = (const unsigned long long*)vin; // 4096 qwords
    unsigned long long* q = (unsigned long long*)vsh;
    #pragma unroll
    for (int k = 0; k < 8; k++) {
        const int i = tid + k * TPB;            // wave-coalesced qwords
        q[i] = __hip_atomic_load(p + i, __ATOMIC_RELAXED,
                                 __HIP_MEMORY_SCOPE_AGENT);
    }
}

// wave b (of 8) reduces batch b: 64 lanes x 4 float4 = 1024 floats.
__device__ __forceinline__ void batch_sums(const float* __restrict__ vsh,
                                           float* __restrict__ svs,
                                           float* __restrict__ s2s, int tid)
{
    const int b = tid >> 6, j = tid & 63;       // wave index == batch index
    float sv = 0.f, s2 = 0.f;
    #pragma unroll
    for (int k = 0; k < 4; k++) {
        const float4 v = *(const float4*)&vsh[b * 1024 + (j + k * 64) * 4];
        sv += v.x + v.y + v.z + v.w;
        s2 += v.x * v.x + v.y * v.y + v.z * v.z + v.w * v.w;
    }
    #pragma unroll
    for (int m = 32; m >= 1; m >>= 1) {         // full 64-lane butterfly
        sv += __shfl_xor(sv, m, 64);
        s2 += __shfl_xor(s2, m, 64);
    }
    if (j == 0) { svs[b] = sv; s2s[b] = s2; }
}

__device__ __forceinline__ void epilogue(
    float acc[8], float bias_o, const float* __restrict__ svs,
    const float* __restrict__ s2s, const float* __restrict__ coeff,
    float* __restrict__ vout, int o, int n_out, int lane, bool coh_store)
{
    #pragma unroll
    for (int b = 0; b < 8; b++) {
        #pragma unroll
        for (int m = 32; m >= 1; m >>= 1)
            acc[b] += __shfl_xor(acc[b], m, 64);
    }
    if (lane < 8) {
        const int b = lane;
        const float dot = acc[b];
        float vj = dot + bias_o;
        vj = vj > 0.f ? vj : 0.f;
        const float r = coeff[4];
        const float outv = vj + r * (coeff[0] * s2s[b] + coeff[1] * dot
                                     + (coeff[2] * vj + coeff[3]) * svs[b]);
        float* dst = vout + (size_t)b * n_out + o;
        if (coh_store)
            __hip_atomic_store(dst, outv, __ATOMIC_RELAXED,
                               __HIP_MEMORY_SCOPE_AGENT);
        else
            *dst = outv;
    }
}

__device__ __forceinline__ void layer_reg(
    const float4 wr[4], float bias_o, const float* __restrict__ vsh,
    const float* __restrict__ svs, const float* __restrict__ s2s,
    const float* __restrict__ coeff,
    float* __restrict__ vout, int o, int n_out, int lane, bool coh_store)
{
    float acc[8] = {0.f, 0.f, 0.f, 0.f, 0.f, 0.f, 0.f, 0.f};
    #pragma unroll
    for (int u = 0; u < 4; u++) {
        const float4 wv = wr[u];
        #pragma unroll
        for (int b = 0; b < 8; b++) {
            const float4 v = *(const float4*)&vsh[b * 1024 + (u * 64 + lane) * 4];
            acc[b] += wv.x * v.x + wv.y * v.y + wv.z * v.z + wv.w * v.w;
        }
    }
    epilogue(acc, bias_o, svs, s2s, coeff, vout, o, n_out, lane, coh_store);
}

__device__ __forceinline__ void layer_lds(
    const float* __restrict__ wlds, float bias_o, const float* __restrict__ vsh,
    const float* __restrict__ svs, const float* __restrict__ s2s,
    const float* __restrict__ coeff,
    float* __restrict__ vout, int o, int n_out, int lane, bool coh_store)
{
    float acc[8] = {0.f, 0.f, 0.f, 0.f, 0.f, 0.f, 0.f, 0.f};
    #pragma unroll
    for (int u = 0; u < 4; u++) {
        const float4 wv = *(const float4*)&wlds[(u * 64 + lane) * 4];
        #pragma unroll
        for (int b = 0; b < 8; b++) {
            const float4 v = *(const float4*)&vsh[b * 1024 + (u * 64 + lane) * 4];
            acc[b] += wv.x * v.x + wv.y * v.y + wv.z * v.z + wv.w * v.w;
        }
    }
    epilogue(acc, bias_o, svs, s2s, coeff, vout, o, n_out, lane, coh_store);
}

// Pure-relaxed grid barrier: NO buffer_wbl2 / buffer_inv anywhere.
// Safe: 128 blocks, 82KB LDS -> exactly 1 block/CU, co-resident by capacity.
// Counters zeroed by the memset dispatch each launch. Visibility argument
// in the header comment.
__device__ __forceinline__ void grid_bar(unsigned* cnt, unsigned nblocks)
{
    __syncthreads();   // s_waitcnt vmcnt(0): block's sc0|sc1 stores COMPLETE
    if (threadIdx.x == 0) {
        __hip_atomic_fetch_add(cnt, 1u, __ATOMIC_RELAXED,
                               __HIP_MEMORY_SCOPE_AGENT);
        while (__hip_atomic_load(cnt, __ATOMIC_RELAXED,
                                 __HIP_MEMORY_SCOPE_AGENT) < nblocks)
            __builtin_amdgcn_s_sleep(1);
    }
    __syncthreads();
}

__global__ __launch_bounds__(TPB) void hebb_fused(
    const float* __restrict__ x,
    const float* __restrict__ W1, const float* __restrict__ b1,
    const float* __restrict__ W2, const float* __restrict__ b2,
    const float* __restrict__ W3, const float* __restrict__ b3,
    const float* __restrict__ cw1, const float* __restrict__ cb1,
    const float* __restrict__ cw2, const float* __restrict__ cb2,
    const int* __restrict__ batch_num,
    float* __restrict__ v1, float* __restrict__ v2, float* __restrict__ out,
    unsigned* __restrict__ bar)
{
    __shared__ __align__(16) float vsh[8 * 1024];   // 32 KB activations
    __shared__ __align__(16) float w2sh[8 * 1024];  // 32 KB: W2 rows, 1/wave
    __shared__ __align__(16) float w3sh[4 * 1024];  // 16 KB: W3 rows (w 0..3)
    __shared__ float coeff[8];
    __shared__ float svs[8], s2s[8];

    const int tid  = threadIdx.x;
    const int w    = tid >> 6, lane = tid & 63;
    const int blk  = blockIdx.x;
    const int o12  = blk * 8 + w;            // layer 1/2 row (0..1023)
    const int o3   = blk * 4 + (w & 3);      // layer 3 row
    const bool act3 = (w < 4);
    const unsigned NB = gridDim.x;

    // ---- t=0: DMA-stage W2/W3 rows into LDS (cannot be sunk past barriers).
    {
        const float* g2 = W2 + (size_t)o12 * 1024 + lane * 4;
        float* l2 = w2sh + w * 1024;                 // wave-uniform dest
        #pragma unroll
        for (int c = 0; c < 4; c++) gl_lds16(g2 + c * 256, l2 + c * 256);
        if (w >= 4) {                                // waves 4..7 stage W3 rows
            const int r = w - 4;
            const float* g3 = W3 + (size_t)(blk * 4 + r) * 1024 + lane * 4;
            float* l3 = w3sh + r * 1024;
            #pragma unroll
            for (int c = 0; c < 4; c++) gl_lds16(g3 + c * 256, l3 + c * 256);
        }
    }

    // ---- layer-1 weight row into registers (16 VGPRs; fits, stays) ----
    float4 w1r[4];
    {
        const float4* r1 = (const float4*)(W1 + (size_t)o12 * 1024);
        #pragma unroll
        for (int u = 0; u < 4; u++) w1r[u] = r1[u * 64 + lane];
    }
    const float bias1 = b1[o12];
    const float bias2 = b2[o12];
    const float bias3 = act3 ? b3[o3] : 0.f;

    stage_v(x, vsh, tid);

    if (tid == 0) {
        float a0 = 0.f, a1 = 0.f, a2 = 0.f, cc = 0.f;
        #pragma unroll
        for (int h = 0; h < 8; h++) {
            const float w2c = cw2[h];
            a0 += w2c * cw1[h * 3 + 0];
            a1 += w2c * cw1[h * 3 + 1];
            a2 += w2c * cw1[h * 3 + 2];
            cc += w2c * cb1[h];
        }
        cc += cb2[0];
        coeff[0] = a0; coeff[1] = a1; coeff[2] = a2; coeff[3] = cc;
        coeff[4] = RATE_F / (float)batch_num[0];
    }
    __syncthreads();
    batch_sums(vsh, svs, s2s, tid);
    __syncthreads();
    layer_reg(w1r, bias1, vsh, svs, s2s, coeff, v1, o12, 1024, lane, true);

    grid_bar(&bar[0], NB);            // counter 0 @ byte 0

    stage_v_coh(v1, vsh, tid);
    __syncthreads();
    batch_sums(vsh, svs, s2s, tid);
    __syncthreads();
    layer_lds(w2sh + w * 1024, bias2, vsh, svs, s2s, coeff, v2, o12, 1024,
              lane, true);

    grid_bar(&bar[32], NB);           // counter 1 @ byte 128 (own cacheline)

    stage_v_coh(v2, vsh, tid);
    __syncthreads();
    batch_sums(vsh, svs, s2s, tid);
    __syncthreads();
    if (act3)
        layer_lds(w3sh + (w & 3) * 1024, bias3, vsh, svs, s2s, coeff, out, o3,
                  512, lane, false);
}

extern "C" void kernel_launch(void* const* d_in, const int* in_sizes, int n_in,
                              void* d_out, int out_size, void* d_ws, size_t ws_size,
                              hipStream_t stream) {
    const float* x   = (const float*)d_in[0];
    const float* W1  = (const float*)d_in[1];
    const float* b1  = (const float*)d_in[2];
    const float* W2  = (const float*)d_in[3];
    const float* b2  = (const float*)d_in[4];
    const float* W3  = (const float*)d_in[5];
    const float* b3  = (const float*)d_in[6];
    const float* cw1 = (const float*)d_in[7];
    const float* cb1 = (const float*)d_in[8];
    const float* cw2 = (const float*)d_in[9];
    const float* cb2 = (const float*)d_in[10];
    const int*   bn  = (const int*)d_in[11];

    float*    v1  = (float*)d_ws;            // 8x1024 fp32 intermediate
    float*    v2  = v1 + 8 * 1024;           // 8x1024 fp32 intermediate
    unsigned* bar = (unsigned*)(v2 + 8 * 1024);  // 2 counters, 128B apart
    float*    out = (float*)d_out;

    hipMemsetAsync(bar, 0, 256, stream);
    hebb_fused<<<NBLK, TPB, 0, stream>>>(x, W1, b1, W2, b2, W3, b3,
                                         cw1, cb1, cw2, cb2, bn,
                                         v1, v2, out, bar);
}